// Round 8
// baseline (210.101 us; speedup 1.0000x reference)
//
#include <hip/hip_runtime.h>
#include <math.h>
#include <stdint.h>

#define PCH 256
#define HD  1024
#define BB  8
#define LL  4096
#define NN  512                  // 2*P
#define MROWS (BB*LL)            // 32768
#define NCH 64                   // number of chunks
#define TCH 64                   // chunk length (NCH*TCH == LL)

typedef __bf16 bf16x8 __attribute__((ext_vector_type(8)));
typedef float  f32x4  __attribute__((ext_vector_type(4)));
typedef short  s16x8  __attribute__((ext_vector_type(8)));

// ---- workspace layout (byte offsets) ----
#define OFFB_W1    ((size_t)0)                          // [NN][HD] bf16 = 1 MB
#define OFFB_C2    (OFFB_W1  + (size_t)NN*HD*2)         // [HD][NN] bf16 = 1 MB
#define OFFB_CST   (OFFB_C2  + (size_t)HD*NN*2)         // 16 KB
#define OFFB_BU    (OFFB_CST + (size_t)16384)           // [M][NN] bf16 = 32 MB
#define OFFB_YS    (OFFB_BU  + (size_t)MROWS*NN*2)      // [M][NN] bf16 = 32 MB
#define OFFB_ZEND  (OFFB_YS  + (size_t)MROWS*NN*2)      // 2 MB
#define OFFB_CARRY (OFFB_ZEND + (size_t)BB*NCH*2*NN*4)  // 2 MB

__device__ __forceinline__ short f2bf(float f) {
    union { float f; uint32_t u; } v; v.f = f;
    uint32_t r = v.u + 0x7FFFu + ((v.u >> 16) & 1u);
    return (short)(r >> 16);
}
__device__ __forceinline__ float bf2f(unsigned short u) {
    union { uint32_t u; float f; } v; v.u = ((uint32_t)u) << 16;
    return v.f;
}

// consts layout: j*PCH + p ; j: 0=m11 1=m12 2=m21 3=m22 4=c1 5=c2 6=mt11 7=mt12 8=mt21 9=mt22
__global__ void prep_consts(const float* __restrict__ steps_raw,
                            const float* __restrict__ G_raw,
                            const float* __restrict__ A_raw,
                            float* __restrict__ cst) {
    int p = threadIdx.x;
    if (p >= PCH) return;
    float steps = 1.0f / (1.0f + expf(-steps_raw[p]));
    float G = fmaxf(G_raw[p], 0.0f);
    float A = fmaxf(A_raw[p], 0.0f);
    float S = 1.0f + steps * G;
    float alpha = steps * steps * A / S;
    alpha = 1.99f * tanhf(alpha / 1.99f);
    float m11 = 1.0f / S;
    float m12 = -alpha / steps;
    float m21 = steps / S;
    float m22 = 1.0f - alpha;
    float c1 = steps / S;
    float c2 = steps * steps / S;
    float a = 1.f, b = 0.f, c = 0.f, d = 1.f;
    for (int i = 0; i < TCH; ++i) {
        float na = m11*a + m12*c;
        float nb = m11*b + m12*d;
        float nc = m21*a + m22*c;
        float nd = m21*b + m22*d;
        a = na; b = nb; c = nc; d = nd;
    }
    cst[0*PCH+p] = m11; cst[1*PCH+p] = m12; cst[2*PCH+p] = m21; cst[3*PCH+p] = m22;
    cst[4*PCH+p] = c1;  cst[5*PCH+p] = c2;
    cst[6*PCH+p] = a;   cst[7*PCH+p] = b;   cst[8*PCH+p] = c;   cst[9*PCH+p] = d;
}

// W1t[n][h] = bf16(B_mat[p][h][t]); C2t[h][n] = bf16(sign(t)*C_mat[h][p][t]); n=2p+t
__global__ void prep_w(const float* __restrict__ B_mat,
                       const float* __restrict__ C_mat,
                       short* __restrict__ W1t,
                       short* __restrict__ C2t) {
    int idx = blockIdx.x * blockDim.x + threadIdx.x;
    if (idx >= HD * NN) return;
    {   // W1t is [NN][HD]
        int n = idx >> 10;
        int h = idx & (HD - 1);
        int p = n >> 1, t = n & 1;
        W1t[idx] = f2bf(B_mat[(size_t)p * HD * 2 + (size_t)h * 2 + t]);
    }
    {   // C2t is [HD][NN]
        int h = idx >> 9;
        int n = idx & (NN - 1);
        int p = n >> 1, t = n & 1;
        float sgn = (t == 0) ? 1.0f : -1.0f;
        C2t[idx] = f2bf(sgn * C_mat[(size_t)h * PCH * 2 + (size_t)p * 2 + t]);
    }
}

// ---- 128x128 bf16 MFMA GEMM (m97-style), BK=32, 4 waves (2x2), 2-phase dbuf.
// C[M x N] = A[M x K] * Bt[N x K]^T.  A is bf16 (global_load_lds) or f32
// (reg-staged with in-flight f32->bf16 convert == fused cvt).  Out f32 or
// bf16; optional epilogue += x*Dv (x f32).
// LDS 32 KB: 2 bufs x (A 8KB + B 8KB). Rows 64 B = 4 x 16B chunks,
// swizzle chunk' = chunk ^ ((row>>1)&3) (involution): applied on pre-swizzled
// global source (linear gl_lds dest) / on the swizzled ds_write address for
// the f32 path, and again on the ds_read address.
template <int K, int N, bool A_F32, bool OUT_BF16, bool EPI>
__global__ __launch_bounds__(256, 3)
void gemm128(const void* __restrict__ Aop, const short* __restrict__ Bt,
             void* __restrict__ Cout, const float* __restrict__ xres,
             const float* __restrict__ Dv) {
    __shared__ alignas(16) char smem[32768];
    constexpr int GX = N / 128;
    // T1: bijective XCD swizzle (gridDim.x % 8 == 0)
    const int nwg = gridDim.x;
    const int cpx = nwg >> 3;
    const int bid = blockIdx.x;
    const int wg = (bid & 7) * cpx + (bid >> 3);
    const int by = wg / GX, bx = wg % GX;
    const int m0 = by * 128, n0 = bx * 128;

    const int tid = threadIdx.x;
    const int lane = tid & 63, w = tid >> 6;
    const int wm = w >> 1, wn = w & 1;            // 2 x 2 wave grid
    const int g = lane >> 4, r16 = lane & 15;

    const short* Abf  = (const short*)Aop;
    const float* Af32 = (const float*)Aop;

    // B staging: 8 KB = 512 chunks of 16B -> 2 per thread (pre-swizzled source)
    auto stageB = [&](int buf, int k0) {
        #pragma unroll
        for (int s = 0; s < 2; ++s) {
            int c = tid + s * 256;
            int row = c >> 2, q = c & 3;
            int gq = q ^ ((row >> 1) & 3);
            const short* sb = Bt + (size_t)(n0 + row) * K + k0 + gq * 8;
            __builtin_amdgcn_global_load_lds(
                (const __attribute__((address_space(1))) void*)sb,
                (__attribute__((address_space(3))) void*)(smem + buf * 16384 + 8192 + c * 16),
                16, 0, 0);
        }
    };
    // A staging, bf16 path
    auto stageAbf = [&](int buf, int k0) {
        #pragma unroll
        for (int s = 0; s < 2; ++s) {
            int c = tid + s * 256;
            int row = c >> 2, q = c & 3;
            int gq = q ^ ((row >> 1) & 3);
            const short* sa = Abf + (size_t)(m0 + row) * K + k0 + gq * 8;
            __builtin_amdgcn_global_load_lds(
                (const __attribute__((address_space(1))) void*)sa,
                (__attribute__((address_space(3))) void*)(smem + buf * 16384 + c * 16),
                16, 0, 0);
        }
    };
    // A staging, f32 path: load f32 to regs (issue-early) ...
    f32x4 av0, av1, av2, av3;
    auto loadAf32 = [&](int k0) {
        {
            int c = tid;               // s=0
            int row = c >> 2, q = c & 3;
            const f32x4* px = (const f32x4*)(Af32 + (size_t)(m0 + row) * K + k0 + q * 8);
            av0 = px[0]; av1 = px[1];
        }
        {
            int c = tid + 256;         // s=1
            int row = c >> 2, q = c & 3;
            const f32x4* px = (const f32x4*)(Af32 + (size_t)(m0 + row) * K + k0 + q * 8);
            av2 = px[0]; av3 = px[1];
        }
    };
    // ... convert + swizzled ds_write (write-late)
    auto writeAf32 = [&](int buf) {
        {
            int c = tid;
            int row = c >> 2, q = c & 3;
            int gq = q ^ ((row >> 1) & 3);
            s16x8 r;
            #pragma unroll
            for (int j = 0; j < 4; ++j) { r[j] = f2bf(av0[j]); r[4 + j] = f2bf(av1[j]); }
            *(s16x8*)(smem + buf * 16384 + row * 64 + gq * 16) = r;
        }
        {
            int c = tid + 256;
            int row = c >> 2, q = c & 3;
            int gq = q ^ ((row >> 1) & 3);
            s16x8 r;
            #pragma unroll
            for (int j = 0; j < 4; ++j) { r[j] = f2bf(av2[j]); r[4 + j] = f2bf(av3[j]); }
            *(s16x8*)(smem + buf * 16384 + row * 64 + gq * 16) = r;
        }
    };

    // fragment read offsets (swizzle depends only on r16 since row-base % 16 == 0)
    const int swzg = (g ^ ((r16 >> 1) & 3)) << 4;
    int aoff[4], boff[4];
    #pragma unroll
    for (int i = 0; i < 4; ++i)
        aoff[i] = (wm * 64 + i * 16 + r16) * 64 + swzg;
    #pragma unroll
    for (int j = 0; j < 4; ++j)
        boff[j] = 8192 + (wn * 64 + j * 16 + r16) * 64 + swzg;

    f32x4 acc[4][4];
    #pragma unroll
    for (int i = 0; i < 4; ++i)
        #pragma unroll
        for (int j = 0; j < 4; ++j) acc[i][j] = (f32x4)0.0f;

    constexpr int NT = K / 32;
    // prologue: fill buf 0
    if (A_F32) { loadAf32(0); stageB(0, 0); writeAf32(0); }
    else       { stageAbf(0, 0); stageB(0, 0); }
    __syncthreads();
    int cur = 0;
    #pragma unroll 1
    for (int t = 0; t < NT; ++t) {
        if (t + 1 < NT) {
            if (A_F32) loadAf32((t + 1) * 32);
            else       stageAbf(cur ^ 1, (t + 1) * 32);
            stageB(cur ^ 1, (t + 1) * 32);
        }
        const char* base = smem + cur * 16384;
        bf16x8 af[4], bfv[4];
        #pragma unroll
        for (int i = 0; i < 4; ++i) af[i] = *(const bf16x8*)(base + aoff[i]);
        #pragma unroll
        for (int j = 0; j < 4; ++j) bfv[j] = *(const bf16x8*)(base + boff[j]);
        #pragma unroll
        for (int i = 0; i < 4; ++i)
            #pragma unroll
            for (int j = 0; j < 4; ++j)
                acc[i][j] = __builtin_amdgcn_mfma_f32_16x16x32_bf16(
                    af[i], bfv[j], acc[i][j], 0, 0, 0);
        if (A_F32 && t + 1 < NT) writeAf32(cur ^ 1);
        __syncthreads();   // drains vmcnt+lgkmcnt: next buf fully staged; cur free
        cur ^= 1;
    }

    // epilogue: C/D map col=lane&15, row=(lane>>4)*4+reg
    const int crow0 = m0 + wm * 64 + g * 4;
    const int ccol0 = n0 + wn * 64 + r16;
    #pragma unroll
    for (int j = 0; j < 4; ++j) {
        int col = ccol0 + j * 16;
        float dv = EPI ? Dv[col] : 0.0f;
        #pragma unroll
        for (int i = 0; i < 4; ++i) {
            #pragma unroll
            for (int r = 0; r < 4; ++r) {
                size_t idx = (size_t)(crow0 + i * 16 + r) * N + col;
                float v = acc[i][j][r];
                if (EPI) v = fmaf(xres[idx], dv, v);
                if (OUT_BF16) ((unsigned short*)Cout)[idx] = (unsigned short)f2bf(v);
                else          ((float*)Cout)[idx] = v;
            }
        }
    }
}

// ---- scan phase 1: zero-init local chunk scans over bf16 Bu ----
__global__ __launch_bounds__(512)
void scan_phase1(const unsigned short* __restrict__ Bu, const float* __restrict__ cst,
                 float* __restrict__ zend) {
    int bid = blockIdx.x;
    int b = bid / NCH, c = bid % NCH;
    int n = threadIdx.x;
    int p = n >> 1;
    float m11 = cst[0*PCH+p], m12 = cst[1*PCH+p], m21 = cst[2*PCH+p], m22 = cst[3*PCH+p];
    float c1 = cst[4*PCH+p], c2 = cst[5*PCH+p];
    float s1 = 0.f, s2 = 0.f;
    const unsigned short* bp = Bu + ((size_t)(b * LL + c * TCH)) * NN + n;
    #pragma unroll 4
    for (int i = 0; i < TCH; ++i) {
        float u = bf2f(bp[(size_t)i * NN]);
        float ns1 = fmaf(m11, s1, fmaf(m12, s2, c1 * u));
        float ns2 = fmaf(m21, s1, fmaf(m22, s2, c2 * u));
        s1 = ns1; s2 = ns2;
    }
    size_t base = ((size_t)(b * NCH + c) * 2) * NN + n;
    zend[base] = s1;
    zend[base + NN] = s2;
}

// ---- scan phase 2: carry_c = z_c + M^TCH * carry_{c-1} ----
__global__ __launch_bounds__(512)
void scan_phase2(const float* __restrict__ zend, const float* __restrict__ cst,
                 float* __restrict__ carry) {
    int b = blockIdx.x;
    int n = threadIdx.x;
    int p = n >> 1;
    float a = cst[6*PCH+p], bm = cst[7*PCH+p], cmt = cst[8*PCH+p], d = cst[9*PCH+p];
    float cs1 = 0.f, cs2 = 0.f;
    for (int c = 0; c < NCH; ++c) {
        size_t base = ((size_t)(b * NCH + c) * 2) * NN + n;
        float z1 = zend[base], z2 = zend[base + NN];
        float ns1 = fmaf(a, cs1, fmaf(bm, cs2, z1));
        float ns2 = fmaf(cmt, cs1, fmaf(d, cs2, z2));
        carry[base] = ns1;
        carry[base + NN] = ns2;
        cs1 = ns1; cs2 = ns2;
    }
}

// ---- scan phase 3: re-run chunks with correct init, write ys = s2 as bf16 ----
__global__ __launch_bounds__(512)
void scan_phase3(const unsigned short* __restrict__ Bu, const float* __restrict__ cst,
                 const float* __restrict__ carry, unsigned short* __restrict__ ys) {
    int bid = blockIdx.x;
    int b = bid / NCH, c = bid % NCH;
    int n = threadIdx.x;
    int p = n >> 1;
    float m11 = cst[0*PCH+p], m12 = cst[1*PCH+p], m21 = cst[2*PCH+p], m22 = cst[3*PCH+p];
    float c1 = cst[4*PCH+p], c2 = cst[5*PCH+p];
    float s1 = 0.f, s2 = 0.f;
    if (c > 0) {
        size_t base = ((size_t)(b * NCH + (c - 1)) * 2) * NN + n;
        s1 = carry[base];
        s2 = carry[base + NN];
    }
    const unsigned short* bp = Bu + ((size_t)(b * LL + c * TCH)) * NN + n;
    unsigned short* yp = ys + ((size_t)(b * LL + c * TCH)) * NN + n;
    #pragma unroll 4
    for (int i = 0; i < TCH; ++i) {
        float u = bf2f(bp[(size_t)i * NN]);
        float ns1 = fmaf(m11, s1, fmaf(m12, s2, c1 * u));
        float ns2 = fmaf(m21, s1, fmaf(m22, s2, c2 * u));
        s1 = ns1; s2 = ns2;
        yp[(size_t)i * NN] = (unsigned short)f2bf(s2);
    }
}

extern "C" void kernel_launch(void* const* d_in, const int* in_sizes, int n_in,
                              void* d_out, int out_size, void* d_ws, size_t ws_size,
                              hipStream_t stream) {
    const float* x         = (const float*)d_in[0];
    const float* steps_raw = (const float*)d_in[1];
    const float* G_raw     = (const float*)d_in[2];
    const float* A_raw     = (const float*)d_in[3];
    const float* B_mat     = (const float*)d_in[4];
    const float* C_mat     = (const float*)d_in[5];
    const float* D_vec     = (const float*)d_in[6];
    float* out = (float*)d_out;
    char*  ws  = (char*)d_ws;

    short*          W1t   = (short*)(ws + OFFB_W1);
    short*          C2t   = (short*)(ws + OFFB_C2);
    float*          cst   = (float*)(ws + OFFB_CST);
    unsigned short* Bu    = (unsigned short*)(ws + OFFB_BU);
    unsigned short* ysbf  = (unsigned short*)(ws + OFFB_YS);
    float*          zend  = (float*)(ws + OFFB_ZEND);
    float*          carry = (float*)(ws + OFFB_CARRY);

    prep_consts<<<1, 256, 0, stream>>>(steps_raw, G_raw, A_raw, cst);
    prep_w<<<(HD * NN) / 512, 512, 0, stream>>>(B_mat, C_mat, W1t, C2t);

    // GEMM1 (fused cvt): Bu[32768 x 512](bf16) = bf16(x) * W1t^T
    // grid = (512/128) x (32768/128) = 4*256 = 1024 blocks
    gemm128<HD, NN, true, true, false><<<(NN / 128) * (MROWS / 128), 256, 0, stream>>>(
        (const void*)x, W1t, (void*)Bu, nullptr, nullptr);

    scan_phase1<<<BB * NCH, 512, 0, stream>>>(Bu, cst, zend);
    scan_phase2<<<BB, 512, 0, stream>>>(zend, cst, carry);
    scan_phase3<<<BB * NCH, 512, 0, stream>>>(Bu, cst, carry, ysbf);

    // GEMM2: out[32768 x 1024](f32) = ysbf * C2t^T + x*D
    // grid = (1024/128) x (32768/128) = 8*256 = 2048 blocks
    gemm128<NN, HD, false, false, true><<<(HD / 128) * (MROWS / 128), 256, 0, stream>>>(
        (const void*)ysbf, C2t, (void*)out, x, D_vec);
}

// Round 9
// 199.114 us; speedup vs baseline: 1.0552x; 1.0552x over previous
//
#include <hip/hip_runtime.h>
#include <math.h>
#include <stdint.h>

#define PCH 256
#define HD  1024
#define BB  8
#define LL  4096
#define NN  512                  // 2*P
#define MROWS (BB*LL)            // 32768
#define NCH 64                   // number of chunks
#define TCH 64                   // chunk length (NCH*TCH == LL)

typedef __bf16 bf16x8 __attribute__((ext_vector_type(8)));
typedef float  f32x4  __attribute__((ext_vector_type(4)));
typedef short  s16x8  __attribute__((ext_vector_type(8)));

// ---- workspace layout (byte offsets) ----
#define OFFB_W1    ((size_t)0)                          // [NN][HD] bf16 = 1 MB
#define OFFB_C2    (OFFB_W1  + (size_t)NN*HD*2)         // [HD][NN] bf16 = 1 MB
#define OFFB_CST   (OFFB_C2  + (size_t)HD*NN*2)         // 16 KB
#define OFFB_BU    (OFFB_CST + (size_t)16384)           // [M][NN] bf16 = 32 MB
#define OFFB_YS    (OFFB_BU  + (size_t)MROWS*NN*2)      // [M][NN] bf16 = 32 MB
#define OFFB_ZEND  (OFFB_YS  + (size_t)MROWS*NN*2)      // 2 MB
#define OFFB_CARRY (OFFB_ZEND + (size_t)BB*NCH*2*NN*4)  // 2 MB

__device__ __forceinline__ short f2bf(float f) {
    union { float f; uint32_t u; } v; v.f = f;
    uint32_t r = v.u + 0x7FFFu + ((v.u >> 16) & 1u);
    return (short)(r >> 16);
}
__device__ __forceinline__ float bf2f(unsigned short u) {
    union { uint32_t u; float f; } v; v.u = ((uint32_t)u) << 16;
    return v.f;
}

// consts layout: j*PCH + p ; j: 0=m11 1=m12 2=m21 3=m22 4=c1 5=c2 6=mt11 7=mt12 8=mt21 9=mt22
__global__ void prep_consts(const float* __restrict__ steps_raw,
                            const float* __restrict__ G_raw,
                            const float* __restrict__ A_raw,
                            float* __restrict__ cst) {
    int p = threadIdx.x;
    if (p >= PCH) return;
    float steps = 1.0f / (1.0f + expf(-steps_raw[p]));
    float G = fmaxf(G_raw[p], 0.0f);
    float A = fmaxf(A_raw[p], 0.0f);
    float S = 1.0f + steps * G;
    float alpha = steps * steps * A / S;
    alpha = 1.99f * tanhf(alpha / 1.99f);
    float m11 = 1.0f / S;
    float m12 = -alpha / steps;
    float m21 = steps / S;
    float m22 = 1.0f - alpha;
    float c1 = steps / S;
    float c2 = steps * steps / S;
    float a = 1.f, b = 0.f, c = 0.f, d = 1.f;
    for (int i = 0; i < TCH; ++i) {
        float na = m11*a + m12*c;
        float nb = m11*b + m12*d;
        float nc = m21*a + m22*c;
        float nd = m21*b + m22*d;
        a = na; b = nb; c = nc; d = nd;
    }
    cst[0*PCH+p] = m11; cst[1*PCH+p] = m12; cst[2*PCH+p] = m21; cst[3*PCH+p] = m22;
    cst[4*PCH+p] = c1;  cst[5*PCH+p] = c2;
    cst[6*PCH+p] = a;   cst[7*PCH+p] = b;   cst[8*PCH+p] = c;   cst[9*PCH+p] = d;
}

// W1t[n][h] = bf16(B_mat[p][h][t]); C2t[h][n] = bf16(sign(t)*C_mat[h][p][t]); n=2p+t
__global__ void prep_w(const float* __restrict__ B_mat,
                       const float* __restrict__ C_mat,
                       short* __restrict__ W1t,
                       short* __restrict__ C2t) {
    int idx = blockIdx.x * blockDim.x + threadIdx.x;
    if (idx >= HD * NN) return;
    {   // W1t is [NN][HD]
        int n = idx >> 10;
        int h = idx & (HD - 1);
        int p = n >> 1, t = n & 1;
        W1t[idx] = f2bf(B_mat[(size_t)p * HD * 2 + (size_t)h * 2 + t]);
    }
    {   // C2t is [HD][NN]
        int h = idx >> 9;
        int n = idx & (NN - 1);
        int p = n >> 1, t = n & 1;
        float sgn = (t == 0) ? 1.0f : -1.0f;
        C2t[idx] = f2bf(sgn * C_mat[(size_t)h * PCH * 2 + (size_t)p * 2 + t]);
    }
}

// ---- 128x128 bf16 MFMA GEMM, BK=32, 4 waves (2x2), 2-phase dbuf, fused
// f32->bf16 convert on the A operand (reg-staged A). Used for GEMM1.
// C[M x N](bf16) = bf16(Af32[M x K]) * Bt[N x K]^T.
// LDS 32 KB: 2 bufs x (A 8KB + B 8KB). Rows 64 B = 4 x 16B chunks,
// swizzle chunk' = chunk ^ ((row>>1)&3) (involution).
template <int K, int N>
__global__ __launch_bounds__(256, 3)
void gemm128_cvtA(const float* __restrict__ Af32, const short* __restrict__ Bt,
                  unsigned short* __restrict__ Cout) {
    __shared__ alignas(16) char smem[32768];
    constexpr int GX = N / 128;
    // T1: bijective XCD swizzle (gridDim.x % 8 == 0)
    const int nwg = gridDim.x;
    const int cpx = nwg >> 3;
    const int bid = blockIdx.x;
    const int wg = (bid & 7) * cpx + (bid >> 3);
    const int by = wg / GX, bx = wg % GX;
    const int m0 = by * 128, n0 = bx * 128;

    const int tid = threadIdx.x;
    const int lane = tid & 63, w = tid >> 6;
    const int wm = w >> 1, wn = w & 1;            // 2 x 2 wave grid
    const int g = lane >> 4, r16 = lane & 15;

    auto stageB = [&](int buf, int k0) {
        #pragma unroll
        for (int s = 0; s < 2; ++s) {
            int c = tid + s * 256;
            int row = c >> 2, q = c & 3;
            int gq = q ^ ((row >> 1) & 3);
            const short* sb = Bt + (size_t)(n0 + row) * K + k0 + gq * 8;
            __builtin_amdgcn_global_load_lds(
                (const __attribute__((address_space(1))) void*)sb,
                (__attribute__((address_space(3))) void*)(smem + buf * 16384 + 8192 + c * 16),
                16, 0, 0);
        }
    };
    // A: load f32 to regs (issue-early) ...
    f32x4 av0, av1, av2, av3;
    auto loadAf32 = [&](int k0) {
        {
            int c = tid;
            int row = c >> 2, q = c & 3;
            const f32x4* px = (const f32x4*)(Af32 + (size_t)(m0 + row) * K + k0 + q * 8);
            av0 = px[0]; av1 = px[1];
        }
        {
            int c = tid + 256;
            int row = c >> 2, q = c & 3;
            const f32x4* px = (const f32x4*)(Af32 + (size_t)(m0 + row) * K + k0 + q * 8);
            av2 = px[0]; av3 = px[1];
        }
    };
    // ... convert + swizzled ds_write (write-late)
    auto writeAf32 = [&](int buf) {
        {
            int c = tid;
            int row = c >> 2, q = c & 3;
            int gq = q ^ ((row >> 1) & 3);
            s16x8 r;
            #pragma unroll
            for (int j = 0; j < 4; ++j) { r[j] = f2bf(av0[j]); r[4 + j] = f2bf(av1[j]); }
            *(s16x8*)(smem + buf * 16384 + row * 64 + gq * 16) = r;
        }
        {
            int c = tid + 256;
            int row = c >> 2, q = c & 3;
            int gq = q ^ ((row >> 1) & 3);
            s16x8 r;
            #pragma unroll
            for (int j = 0; j < 4; ++j) { r[j] = f2bf(av2[j]); r[4 + j] = f2bf(av3[j]); }
            *(s16x8*)(smem + buf * 16384 + row * 64 + gq * 16) = r;
        }
    };

    const int swzg = (g ^ ((r16 >> 1) & 3)) << 4;
    int aoff[4], boff[4];
    #pragma unroll
    for (int i = 0; i < 4; ++i)
        aoff[i] = (wm * 64 + i * 16 + r16) * 64 + swzg;
    #pragma unroll
    for (int j = 0; j < 4; ++j)
        boff[j] = 8192 + (wn * 64 + j * 16 + r16) * 64 + swzg;

    f32x4 acc[4][4];
    #pragma unroll
    for (int i = 0; i < 4; ++i)
        #pragma unroll
        for (int j = 0; j < 4; ++j) acc[i][j] = (f32x4)0.0f;

    constexpr int NT = K / 32;
    loadAf32(0); stageB(0, 0); writeAf32(0);
    __syncthreads();
    int cur = 0;
    #pragma unroll 1
    for (int t = 0; t < NT; ++t) {
        if (t + 1 < NT) {
            loadAf32((t + 1) * 32);
            stageB(cur ^ 1, (t + 1) * 32);
        }
        const char* base = smem + cur * 16384;
        bf16x8 af[4], bfv[4];
        #pragma unroll
        for (int i = 0; i < 4; ++i) af[i] = *(const bf16x8*)(base + aoff[i]);
        #pragma unroll
        for (int j = 0; j < 4; ++j) bfv[j] = *(const bf16x8*)(base + boff[j]);
        #pragma unroll
        for (int i = 0; i < 4; ++i)
            #pragma unroll
            for (int j = 0; j < 4; ++j)
                acc[i][j] = __builtin_amdgcn_mfma_f32_16x16x32_bf16(
                    af[i], bfv[j], acc[i][j], 0, 0, 0);
        if (t + 1 < NT) writeAf32(cur ^ 1);
        __syncthreads();
        cur ^= 1;
    }

    const int crow0 = m0 + wm * 64 + g * 4;
    const int ccol0 = n0 + wn * 64 + r16;
    #pragma unroll
    for (int j = 0; j < 4; ++j) {
        int col = ccol0 + j * 16;
        #pragma unroll
        for (int i = 0; i < 4; ++i) {
            #pragma unroll
            for (int r = 0; r < 4; ++r) {
                size_t idx = (size_t)(crow0 + i * 16 + r) * N + col;
                Cout[idx] = (unsigned short)f2bf(acc[i][j][r]);
            }
        }
    }
}

// ---- 256x256 bf16 MFMA GEMM, BK=64, 8 waves (2Mx4N), 2-phase dbuf (round-3
// verified, 81 us). Used for GEMM2. C[M x N](f32) = A * Bt^T + x*Dv.
// LDS 128KB: 2 bufs x (A 32KB + B 32KB). Rows 128B (8 x 16B chunks);
// swizzle chunk' = chunk ^ (row&7) (involution; pre-swizzled global source,
// linear global_load_lds dest, swizzled ds_read).
template <int K, int N, bool EPI>
__global__ __launch_bounds__(512, 2)
void gemm256(const short* __restrict__ A, const short* __restrict__ Bt,
             float* __restrict__ Cout, const float* __restrict__ xres,
             const float* __restrict__ Dv) {
    __shared__ alignas(16) char smem[131072];
    constexpr int GX = N / 256;
    const int nwg = gridDim.x;
    const int cpx = nwg >> 3;
    const int bid = blockIdx.x;
    const int wg = (bid & 7) * cpx + (bid >> 3);
    const int by = wg / GX, bx = wg % GX;
    const int m0 = by * 256, n0 = bx * 256;

    const int tid = threadIdx.x;
    const int lane = tid & 63, w = tid >> 6;
    const int wm = w >> 2, wn = w & 3;            // 2 x 4 wave grid
    const int g = lane >> 4, r16 = lane & 15;

    auto stage = [&](int buf, int k0) {
        #pragma unroll
        for (int s = 0; s < 4; ++s) {
            int c = tid + s * 512;                 // 0..2047 (256 rows x 8 chunks)
            int row = c >> 3, q = c & 7;
            int gq = q ^ (row & 7);
            const short* sa = A + (size_t)(m0 + row) * K + k0 + gq * 8;
            __builtin_amdgcn_global_load_lds(
                (const __attribute__((address_space(1))) void*)sa,
                (__attribute__((address_space(3))) void*)(smem + buf * 65536 + c * 16),
                16, 0, 0);
        }
        #pragma unroll
        for (int s = 0; s < 4; ++s) {
            int c = tid + s * 512;
            int row = c >> 3, q = c & 7;
            int gq = q ^ (row & 7);
            const short* sb = Bt + (size_t)(n0 + row) * K + k0 + gq * 8;
            __builtin_amdgcn_global_load_lds(
                (const __attribute__((address_space(1))) void*)sb,
                (__attribute__((address_space(3))) void*)(smem + buf * 65536 + 32768 + c * 16),
                16, 0, 0);
        }
    };

    // fragment read offsets for kk=0; kk=1 address = kk=0 address ^ 64
    int aoff[8], boff[4];
    #pragma unroll
    for (int mi = 0; mi < 8; ++mi) {
        int ra = wm * 128 + mi * 16 + r16;
        aoff[mi] = ra * 128 + ((g ^ (ra & 7)) << 4);
    }
    #pragma unroll
    for (int nj = 0; nj < 4; ++nj) {
        int rb = wn * 64 + nj * 16 + r16;
        boff[nj] = 32768 + rb * 128 + ((g ^ (rb & 7)) << 4);
    }

    f32x4 acc[8][4];
    #pragma unroll
    for (int mi = 0; mi < 8; ++mi)
        #pragma unroll
        for (int nj = 0; nj < 4; ++nj) acc[mi][nj] = (f32x4)0.0f;

    constexpr int NT = K / 64;
    stage(0, 0);
    __syncthreads();
    int cur = 0;
    #pragma unroll 1
    for (int t = 0; t < NT; ++t) {
        if (t + 1 < NT) stage(cur ^ 1, (t + 1) * 64);
        const char* base = smem + cur * 65536;
        #pragma unroll
        for (int kk = 0; kk < 2; ++kk) {
            bf16x8 af[8], bfv[4];
            #pragma unroll
            for (int mi = 0; mi < 8; ++mi)
                af[mi] = *(const bf16x8*)(base + (aoff[mi] ^ (kk << 6)));
            #pragma unroll
            for (int nj = 0; nj < 4; ++nj)
                bfv[nj] = *(const bf16x8*)(base + (boff[nj] ^ (kk << 6)));
            #pragma unroll
            for (int mi = 0; mi < 8; ++mi)
                #pragma unroll
                for (int nj = 0; nj < 4; ++nj)
                    acc[mi][nj] = __builtin_amdgcn_mfma_f32_16x16x32_bf16(
                        af[mi], bfv[nj], acc[mi][nj], 0, 0, 0);
        }
        __syncthreads();
        cur ^= 1;
    }

    const int crow0 = m0 + wm * 128 + g * 4;
    const int ccol0 = n0 + wn * 64 + r16;
    #pragma unroll
    for (int nj = 0; nj < 4; ++nj) {
        int col = ccol0 + nj * 16;
        float dv = EPI ? Dv[col] : 0.0f;
        #pragma unroll
        for (int mi = 0; mi < 8; ++mi) {
            #pragma unroll
            for (int r = 0; r < 4; ++r) {
                size_t idx = (size_t)(crow0 + mi * 16 + r) * N + col;
                float v = acc[mi][nj][r];
                if (EPI) v = fmaf(xres[idx], dv, v);
                Cout[idx] = v;
            }
        }
    }
}

// ---- scan phase 1: zero-init local chunk scans over bf16 Bu ----
__global__ __launch_bounds__(512)
void scan_phase1(const unsigned short* __restrict__ Bu, const float* __restrict__ cst,
                 float* __restrict__ zend) {
    int bid = blockIdx.x;
    int b = bid / NCH, c = bid % NCH;
    int n = threadIdx.x;
    int p = n >> 1;
    float m11 = cst[0*PCH+p], m12 = cst[1*PCH+p], m21 = cst[2*PCH+p], m22 = cst[3*PCH+p];
    float c1 = cst[4*PCH+p], c2 = cst[5*PCH+p];
    float s1 = 0.f, s2 = 0.f;
    const unsigned short* bp = Bu + ((size_t)(b * LL + c * TCH)) * NN + n;
    #pragma unroll 4
    for (int i = 0; i < TCH; ++i) {
        float u = bf2f(bp[(size_t)i * NN]);
        float ns1 = fmaf(m11, s1, fmaf(m12, s2, c1 * u));
        float ns2 = fmaf(m21, s1, fmaf(m22, s2, c2 * u));
        s1 = ns1; s2 = ns2;
    }
    size_t base = ((size_t)(b * NCH + c) * 2) * NN + n;
    zend[base] = s1;
    zend[base + NN] = s2;
}

// ---- scan phase 2: carry_c = z_c + M^TCH * carry_{c-1} ----
__global__ __launch_bounds__(512)
void scan_phase2(const float* __restrict__ zend, const float* __restrict__ cst,
                 float* __restrict__ carry) {
    int b = blockIdx.x;
    int n = threadIdx.x;
    int p = n >> 1;
    float a = cst[6*PCH+p], bm = cst[7*PCH+p], cmt = cst[8*PCH+p], d = cst[9*PCH+p];
    float cs1 = 0.f, cs2 = 0.f;
    for (int c = 0; c < NCH; ++c) {
        size_t base = ((size_t)(b * NCH + c) * 2) * NN + n;
        float z1 = zend[base], z2 = zend[base + NN];
        float ns1 = fmaf(a, cs1, fmaf(bm, cs2, z1));
        float ns2 = fmaf(cmt, cs1, fmaf(d, cs2, z2));
        carry[base] = ns1;
        carry[base + NN] = ns2;
        cs1 = ns1; cs2 = ns2;
    }
}

// ---- scan phase 3: re-run chunks with correct init, write ys = s2 as bf16 ----
__global__ __launch_bounds__(512)
void scan_phase3(const unsigned short* __restrict__ Bu, const float* __restrict__ cst,
                 const float* __restrict__ carry, unsigned short* __restrict__ ys) {
    int bid = blockIdx.x;
    int b = bid / NCH, c = bid % NCH;
    int n = threadIdx.x;
    int p = n >> 1;
    float m11 = cst[0*PCH+p], m12 = cst[1*PCH+p], m21 = cst[2*PCH+p], m22 = cst[3*PCH+p];
    float c1 = cst[4*PCH+p], c2 = cst[5*PCH+p];
    float s1 = 0.f, s2 = 0.f;
    if (c > 0) {
        size_t base = ((size_t)(b * NCH + (c - 1)) * 2) * NN + n;
        s1 = carry[base];
        s2 = carry[base + NN];
    }
    const unsigned short* bp = Bu + ((size_t)(b * LL + c * TCH)) * NN + n;
    unsigned short* yp = ys + ((size_t)(b * LL + c * TCH)) * NN + n;
    #pragma unroll 4
    for (int i = 0; i < TCH; ++i) {
        float u = bf2f(bp[(size_t)i * NN]);
        float ns1 = fmaf(m11, s1, fmaf(m12, s2, c1 * u));
        float ns2 = fmaf(m21, s1, fmaf(m22, s2, c2 * u));
        s1 = ns1; s2 = ns2;
        yp[(size_t)i * NN] = (unsigned short)f2bf(s2);
    }
}

extern "C" void kernel_launch(void* const* d_in, const int* in_sizes, int n_in,
                              void* d_out, int out_size, void* d_ws, size_t ws_size,
                              hipStream_t stream) {
    const float* x         = (const float*)d_in[0];
    const float* steps_raw = (const float*)d_in[1];
    const float* G_raw     = (const float*)d_in[2];
    const float* A_raw     = (const float*)d_in[3];
    const float* B_mat     = (const float*)d_in[4];
    const float* C_mat     = (const float*)d_in[5];
    const float* D_vec     = (const float*)d_in[6];
    float* out = (float*)d_out;
    char*  ws  = (char*)d_ws;

    short*          W1t   = (short*)(ws + OFFB_W1);
    short*          C2t   = (short*)(ws + OFFB_C2);
    float*          cst   = (float*)(ws + OFFB_CST);
    unsigned short* Bu    = (unsigned short*)(ws + OFFB_BU);
    unsigned short* ysbf  = (unsigned short*)(ws + OFFB_YS);
    float*          zend  = (float*)(ws + OFFB_ZEND);
    float*          carry = (float*)(ws + OFFB_CARRY);

    prep_consts<<<1, 256, 0, stream>>>(steps_raw, G_raw, A_raw, cst);
    prep_w<<<(HD * NN) / 512, 512, 0, stream>>>(B_mat, C_mat, W1t, C2t);

    // GEMM1 (fused cvt): Bu[32768 x 512](bf16) = bf16(x) * W1t^T ; 1024 blocks
    gemm128_cvtA<HD, NN><<<(NN / 128) * (MROWS / 128), 256, 0, stream>>>(
        x, W1t, Bu);

    scan_phase1<<<BB * NCH, 512, 0, stream>>>(Bu, cst, zend);
    scan_phase2<<<BB, 512, 0, stream>>>(zend, cst, carry);
    scan_phase3<<<BB * NCH, 512, 0, stream>>>(Bu, cst, carry, ysbf);

    // GEMM2: out[32768 x 1024](f32) = ysbf * C2t^T + x*D ; 512 blocks (256^2)
    gemm256<NN, HD, true><<<(HD / 256) * (MROWS / 256), 512, 0, stream>>>(
        (const short*)ysbf, C2t, out, x, D_vec);
}

// Round 10
// 180.604 us; speedup vs baseline: 1.1633x; 1.1025x over previous
//
#include <hip/hip_runtime.h>
#include <math.h>
#include <stdint.h>

#define PCH 256
#define HD  1024
#define BB  8
#define LL  4096
#define NN  512                  // 2*P
#define MROWS (BB*LL)            // 32768
#define NCH 64                   // number of chunks
#define TCH 64                   // chunk length (NCH*TCH == LL)

typedef __bf16 bf16x8 __attribute__((ext_vector_type(8)));
typedef float  f32x4  __attribute__((ext_vector_type(4)));
typedef short  s16x8  __attribute__((ext_vector_type(8)));

// ---- workspace layout (byte offsets) ----
#define OFFB_W1    ((size_t)0)                          // [NN][HD] bf16 = 1 MB
#define OFFB_C2    (OFFB_W1  + (size_t)NN*HD*2)         // [HD][NN] bf16 = 1 MB
#define OFFB_CST   (OFFB_C2  + (size_t)HD*NN*2)         // 16 KB
#define OFFB_BU    (OFFB_CST + (size_t)16384)           // [M][NN] bf16 = 32 MB
#define OFFB_YS    (OFFB_BU  + (size_t)MROWS*NN*2)      // [M][NN] bf16 = 32 MB
#define OFFB_ZEND  (OFFB_YS  + (size_t)MROWS*NN*2)      // 2 MB
#define OFFB_CARRY (OFFB_ZEND + (size_t)BB*NCH*2*NN*4)  // 2 MB

__device__ __forceinline__ short f2bf(float f) {
    union { float f; uint32_t u; } v; v.f = f;
    uint32_t r = v.u + 0x7FFFu + ((v.u >> 16) & 1u);
    return (short)(r >> 16);
}
__device__ __forceinline__ float bf2f(unsigned short u) {
    union { uint32_t u; float f; } v; v.u = ((uint32_t)u) << 16;
    return v.f;
}

// consts layout: j*PCH + p ; j: 0=m11 1=m12 2=m21 3=m22 4=c1 5=c2 6=mt11 7=mt12 8=mt21 9=mt22
__global__ void prep_consts(const float* __restrict__ steps_raw,
                            const float* __restrict__ G_raw,
                            const float* __restrict__ A_raw,
                            float* __restrict__ cst) {
    int p = threadIdx.x;
    if (p >= PCH) return;
    float steps = 1.0f / (1.0f + expf(-steps_raw[p]));
    float G = fmaxf(G_raw[p], 0.0f);
    float A = fmaxf(A_raw[p], 0.0f);
    float S = 1.0f + steps * G;
    float alpha = steps * steps * A / S;
    alpha = 1.99f * tanhf(alpha / 1.99f);
    float m11 = 1.0f / S;
    float m12 = -alpha / steps;
    float m21 = steps / S;
    float m22 = 1.0f - alpha;
    float c1 = steps / S;
    float c2 = steps * steps / S;
    float a = 1.f, b = 0.f, c = 0.f, d = 1.f;
    for (int i = 0; i < TCH; ++i) {
        float na = m11*a + m12*c;
        float nb = m11*b + m12*d;
        float nc = m21*a + m22*c;
        float nd = m21*b + m22*d;
        a = na; b = nb; c = nc; d = nd;
    }
    cst[0*PCH+p] = m11; cst[1*PCH+p] = m12; cst[2*PCH+p] = m21; cst[3*PCH+p] = m22;
    cst[4*PCH+p] = c1;  cst[5*PCH+p] = c2;
    cst[6*PCH+p] = a;   cst[7*PCH+p] = b;   cst[8*PCH+p] = c;   cst[9*PCH+p] = d;
}

// W1t[n][h] = bf16(B_mat[p][h][t]); C2t[h][n] = bf16(sign(t)*C_mat[h][p][t]); n=2p+t
__global__ void prep_w(const float* __restrict__ B_mat,
                       const float* __restrict__ C_mat,
                       short* __restrict__ W1t,
                       short* __restrict__ C2t) {
    int idx = blockIdx.x * blockDim.x + threadIdx.x;
    if (idx >= HD * NN) return;
    {   // W1t is [NN][HD]
        int n = idx >> 10;
        int h = idx & (HD - 1);
        int p = n >> 1, t = n & 1;
        W1t[idx] = f2bf(B_mat[(size_t)p * HD * 2 + (size_t)h * 2 + t]);
    }
    {   // C2t is [HD][NN]
        int h = idx >> 9;
        int n = idx & (NN - 1);
        int p = n >> 1, t = n & 1;
        float sgn = (t == 0) ? 1.0f : -1.0f;
        C2t[idx] = f2bf(sgn * C_mat[(size_t)h * PCH * 2 + (size_t)p * 2 + t]);
    }
}

// ---- GEMM1: 256x256 bf16 MFMA GEMM, BK=64, 8 waves (2Mx4N), 2-phase dbuf,
// FUSED f32->bf16 on the A operand (reg-staged, issue-early / write-late).
// C[M x N](bf16) = bf16(Af32[M x K]) * Bt[N x K]^T.
// LDS 128KB: 2 bufs x (A 32KB + B 32KB). Rows 128B (8 x 16B chunks);
// involution swizzle chunk' = chunk ^ (row&7): A applies it by loading
// global chunk q^(row&7) and ds_writing linear chunk q; B applies it by
// pre-swizzling the global_load_lds source; ds_read applies it again.
template <int K, int N>
__global__ __launch_bounds__(512, 2)
void gemm256_cvtA(const float* __restrict__ Af32, const short* __restrict__ Bt,
                  unsigned short* __restrict__ Cout) {
    __shared__ alignas(16) char smem[131072];
    constexpr int GX = N / 256;
    const int nwg = gridDim.x;
    const int cpx = nwg >> 3;
    const int bid = blockIdx.x;
    const int wg = (bid & 7) * cpx + (bid >> 3);
    const int by = wg / GX, bx = wg % GX;
    const int m0 = by * 256, n0 = bx * 256;

    const int tid = threadIdx.x;
    const int lane = tid & 63, w = tid >> 6;
    const int wm = w >> 2, wn = w & 3;            // 2 x 4 wave grid
    const int g = lane >> 4, r16 = lane & 15;

    // B staging: 32 KB = 2048 chunks -> 4 per thread, pre-swizzled source
    auto stageB = [&](int buf, int k0) {
        #pragma unroll
        for (int s = 0; s < 4; ++s) {
            int c = tid + s * 512;
            int row = c >> 3, q = c & 7;
            int gq = q ^ (row & 7);
            const short* sb = Bt + (size_t)(n0 + row) * K + k0 + gq * 8;
            __builtin_amdgcn_global_load_lds(
                (const __attribute__((address_space(1))) void*)sb,
                (__attribute__((address_space(3))) void*)(smem + buf * 65536 + 32768 + c * 16),
                16, 0, 0);
        }
    };
    // A: issue f32 loads early (each thread: 4 chunks x 8 f32)
    f32x4 av[4][2];
    auto loadA = [&](int k0) {
        #pragma unroll
        for (int s = 0; s < 4; ++s) {
            int c = tid + s * 512;
            int row = c >> 3, q = c & 7;
            int gq = q ^ (row & 7);
            const f32x4* px = (const f32x4*)(Af32 + (size_t)(m0 + row) * K + k0 + gq * 8);
            av[s][0] = px[0]; av[s][1] = px[1];
        }
    };
    // ... convert + linear ds_write (write-late); LDS[row][q] = global chunk q^(row&7)
    auto writeA = [&](int buf) {
        #pragma unroll
        for (int s = 0; s < 4; ++s) {
            int c = tid + s * 512;
            int row = c >> 3, q = c & 7;
            s16x8 r;
            #pragma unroll
            for (int j = 0; j < 4; ++j) { r[j] = f2bf(av[s][0][j]); r[4 + j] = f2bf(av[s][1][j]); }
            *(s16x8*)(smem + buf * 65536 + row * 128 + q * 16) = r;
        }
    };

    // fragment read offsets for kk=0; kk=1 address = kk=0 address ^ 64
    int aoff[8], boff[4];
    #pragma unroll
    for (int mi = 0; mi < 8; ++mi) {
        int ra = wm * 128 + mi * 16 + r16;
        aoff[mi] = ra * 128 + ((g ^ (ra & 7)) << 4);
    }
    #pragma unroll
    for (int nj = 0; nj < 4; ++nj) {
        int rb = wn * 64 + nj * 16 + r16;
        boff[nj] = 32768 + rb * 128 + ((g ^ (rb & 7)) << 4);
    }

    f32x4 acc[8][4];
    #pragma unroll
    for (int mi = 0; mi < 8; ++mi)
        #pragma unroll
        for (int nj = 0; nj < 4; ++nj) acc[mi][nj] = (f32x4)0.0f;

    constexpr int NT = K / 64;
    loadA(0); stageB(0, 0); writeA(0);
    __syncthreads();
    int cur = 0;
    #pragma unroll 1
    for (int t = 0; t < NT; ++t) {
        if (t + 1 < NT) {
            loadA((t + 1) * 64);                  // issue-early (regs)
            stageB(cur ^ 1, (t + 1) * 64);        // direct-to-LDS
        }
        const char* base = smem + cur * 65536;
        #pragma unroll
        for (int kk = 0; kk < 2; ++kk) {
            bf16x8 af[8], bfv[4];
            #pragma unroll
            for (int mi = 0; mi < 8; ++mi)
                af[mi] = *(const bf16x8*)(base + (aoff[mi] ^ (kk << 6)));
            #pragma unroll
            for (int nj = 0; nj < 4; ++nj)
                bfv[nj] = *(const bf16x8*)(base + (boff[nj] ^ (kk << 6)));
            #pragma unroll
            for (int mi = 0; mi < 8; ++mi)
                #pragma unroll
                for (int nj = 0; nj < 4; ++nj)
                    acc[mi][nj] = __builtin_amdgcn_mfma_f32_16x16x32_bf16(
                        af[mi], bfv[nj], acc[mi][nj], 0, 0, 0);
        }
        if (t + 1 < NT) writeA(cur ^ 1);          // write-late (HBM latency hidden by MFMA)
        __syncthreads();
        cur ^= 1;
    }

    const int crow0 = m0 + wm * 128 + g * 4;
    const int ccol0 = n0 + wn * 64 + r16;
    #pragma unroll
    for (int nj = 0; nj < 4; ++nj) {
        int col = ccol0 + nj * 16;
        #pragma unroll
        for (int mi = 0; mi < 8; ++mi) {
            #pragma unroll
            for (int r = 0; r < 4; ++r) {
                size_t idx = (size_t)(crow0 + mi * 16 + r) * N + col;
                Cout[idx] = (unsigned short)f2bf(acc[mi][nj][r]);
            }
        }
    }
}

// ---- GEMM2: 256x256 bf16 MFMA GEMM, BK=64, 8 waves, 2-phase dbuf.
// C[M x N](f32) = A(bf16) * Bt^T + x*Dv.
template <int K, int N, bool EPI>
__global__ __launch_bounds__(512, 2)
void gemm256(const short* __restrict__ A, const short* __restrict__ Bt,
             float* __restrict__ Cout, const float* __restrict__ xres,
             const float* __restrict__ Dv) {
    __shared__ alignas(16) char smem[131072];
    constexpr int GX = N / 256;
    const int nwg = gridDim.x;
    const int cpx = nwg >> 3;
    const int bid = blockIdx.x;
    const int wg = (bid & 7) * cpx + (bid >> 3);
    const int by = wg / GX, bx = wg % GX;
    const int m0 = by * 256, n0 = bx * 256;

    const int tid = threadIdx.x;
    const int lane = tid & 63, w = tid >> 6;
    const int wm = w >> 2, wn = w & 3;            // 2 x 4 wave grid
    const int g = lane >> 4, r16 = lane & 15;

    auto stage = [&](int buf, int k0) {
        #pragma unroll
        for (int s = 0; s < 4; ++s) {
            int c = tid + s * 512;                 // 0..2047 (256 rows x 8 chunks)
            int row = c >> 3, q = c & 7;
            int gq = q ^ (row & 7);
            const short* sa = A + (size_t)(m0 + row) * K + k0 + gq * 8;
            __builtin_amdgcn_global_load_lds(
                (const __attribute__((address_space(1))) void*)sa,
                (__attribute__((address_space(3))) void*)(smem + buf * 65536 + c * 16),
                16, 0, 0);
        }
        #pragma unroll
        for (int s = 0; s < 4; ++s) {
            int c = tid + s * 512;
            int row = c >> 3, q = c & 7;
            int gq = q ^ (row & 7);
            const short* sb = Bt + (size_t)(n0 + row) * K + k0 + gq * 8;
            __builtin_amdgcn_global_load_lds(
                (const __attribute__((address_space(1))) void*)sb,
                (__attribute__((address_space(3))) void*)(smem + buf * 65536 + 32768 + c * 16),
                16, 0, 0);
        }
    };

    int aoff[8], boff[4];
    #pragma unroll
    for (int mi = 0; mi < 8; ++mi) {
        int ra = wm * 128 + mi * 16 + r16;
        aoff[mi] = ra * 128 + ((g ^ (ra & 7)) << 4);
    }
    #pragma unroll
    for (int nj = 0; nj < 4; ++nj) {
        int rb = wn * 64 + nj * 16 + r16;
        boff[nj] = 32768 + rb * 128 + ((g ^ (rb & 7)) << 4);
    }

    f32x4 acc[8][4];
    #pragma unroll
    for (int mi = 0; mi < 8; ++mi)
        #pragma unroll
        for (int nj = 0; nj < 4; ++nj) acc[mi][nj] = (f32x4)0.0f;

    constexpr int NT = K / 64;
    stage(0, 0);
    __syncthreads();
    int cur = 0;
    #pragma unroll 1
    for (int t = 0; t < NT; ++t) {
        if (t + 1 < NT) stage(cur ^ 1, (t + 1) * 64);
        const char* base = smem + cur * 65536;
        #pragma unroll
        for (int kk = 0; kk < 2; ++kk) {
            bf16x8 af[8], bfv[4];
            #pragma unroll
            for (int mi = 0; mi < 8; ++mi)
                af[mi] = *(const bf16x8*)(base + (aoff[mi] ^ (kk << 6)));
            #pragma unroll
            for (int nj = 0; nj < 4; ++nj)
                bfv[nj] = *(const bf16x8*)(base + (boff[nj] ^ (kk << 6)));
            #pragma unroll
            for (int mi = 0; mi < 8; ++mi)
                #pragma unroll
                for (int nj = 0; nj < 4; ++nj)
                    acc[mi][nj] = __builtin_amdgcn_mfma_f32_16x16x32_bf16(
                        af[mi], bfv[nj], acc[mi][nj], 0, 0, 0);
        }
        __syncthreads();
        cur ^= 1;
    }

    const int crow0 = m0 + wm * 128 + g * 4;
    const int ccol0 = n0 + wn * 64 + r16;
    #pragma unroll
    for (int nj = 0; nj < 4; ++nj) {
        int col = ccol0 + nj * 16;
        float dv = EPI ? Dv[col] : 0.0f;
        #pragma unroll
        for (int mi = 0; mi < 8; ++mi) {
            #pragma unroll
            for (int r = 0; r < 4; ++r) {
                size_t idx = (size_t)(crow0 + mi * 16 + r) * N + col;
                float v = acc[mi][nj][r];
                if (EPI) v = fmaf(xres[idx], dv, v);
                Cout[idx] = v;
            }
        }
    }
}

// ---- scan phase 1: zero-init local chunk scans over bf16 Bu ----
__global__ __launch_bounds__(512)
void scan_phase1(const unsigned short* __restrict__ Bu, const float* __restrict__ cst,
                 float* __restrict__ zend) {
    int bid = blockIdx.x;
    int b = bid / NCH, c = bid % NCH;
    int n = threadIdx.x;
    int p = n >> 1;
    float m11 = cst[0*PCH+p], m12 = cst[1*PCH+p], m21 = cst[2*PCH+p], m22 = cst[3*PCH+p];
    float c1 = cst[4*PCH+p], c2 = cst[5*PCH+p];
    float s1 = 0.f, s2 = 0.f;
    const unsigned short* bp = Bu + ((size_t)(b * LL + c * TCH)) * NN + n;
    #pragma unroll 4
    for (int i = 0; i < TCH; ++i) {
        float u = bf2f(bp[(size_t)i * NN]);
        float ns1 = fmaf(m11, s1, fmaf(m12, s2, c1 * u));
        float ns2 = fmaf(m21, s1, fmaf(m22, s2, c2 * u));
        s1 = ns1; s2 = ns2;
    }
    size_t base = ((size_t)(b * NCH + c) * 2) * NN + n;
    zend[base] = s1;
    zend[base + NN] = s2;
}

// ---- scan phase 2: carry_c = z_c + M^TCH * carry_{c-1} ----
__global__ __launch_bounds__(512)
void scan_phase2(const float* __restrict__ zend, const float* __restrict__ cst,
                 float* __restrict__ carry) {
    int b = blockIdx.x;
    int n = threadIdx.x;
    int p = n >> 1;
    float a = cst[6*PCH+p], bm = cst[7*PCH+p], cmt = cst[8*PCH+p], d = cst[9*PCH+p];
    float cs1 = 0.f, cs2 = 0.f;
    for (int c = 0; c < NCH; ++c) {
        size_t base = ((size_t)(b * NCH + c) * 2) * NN + n;
        float z1 = zend[base], z2 = zend[base + NN];
        float ns1 = fmaf(a, cs1, fmaf(bm, cs2, z1));
        float ns2 = fmaf(cmt, cs1, fmaf(d, cs2, z2));
        carry[base] = ns1;
        carry[base + NN] = ns2;
        cs1 = ns1; cs2 = ns2;
    }
}

// ---- scan phase 3: re-run chunks with correct init, write ys = s2 as bf16 ----
__global__ __launch_bounds__(512)
void scan_phase3(const unsigned short* __restrict__ Bu, const float* __restrict__ cst,
                 const float* __restrict__ carry, unsigned short* __restrict__ ys) {
    int bid = blockIdx.x;
    int b = bid / NCH, c = bid % NCH;
    int n = threadIdx.x;
    int p = n >> 1;
    float m11 = cst[0*PCH+p], m12 = cst[1*PCH+p], m21 = cst[2*PCH+p], m22 = cst[3*PCH+p];
    float c1 = cst[4*PCH+p], c2 = cst[5*PCH+p];
    float s1 = 0.f, s2 = 0.f;
    if (c > 0) {
        size_t base = ((size_t)(b * NCH + (c - 1)) * 2) * NN + n;
        s1 = carry[base];
        s2 = carry[base + NN];
    }
    const unsigned short* bp = Bu + ((size_t)(b * LL + c * TCH)) * NN + n;
    unsigned short* yp = ys + ((size_t)(b * LL + c * TCH)) * NN + n;
    #pragma unroll 4
    for (int i = 0; i < TCH; ++i) {
        float u = bf2f(bp[(size_t)i * NN]);
        float ns1 = fmaf(m11, s1, fmaf(m12, s2, c1 * u));
        float ns2 = fmaf(m21, s1, fmaf(m22, s2, c2 * u));
        s1 = ns1; s2 = ns2;
        yp[(size_t)i * NN] = (unsigned short)f2bf(s2);
    }
}

extern "C" void kernel_launch(void* const* d_in, const int* in_sizes, int n_in,
                              void* d_out, int out_size, void* d_ws, size_t ws_size,
                              hipStream_t stream) {
    const float* x         = (const float*)d_in[0];
    const float* steps_raw = (const float*)d_in[1];
    const float* G_raw     = (const float*)d_in[2];
    const float* A_raw     = (const float*)d_in[3];
    const float* B_mat     = (const float*)d_in[4];
    const float* C_mat     = (const float*)d_in[5];
    const float* D_vec     = (const float*)d_in[6];
    float* out = (float*)d_out;
    char*  ws  = (char*)d_ws;

    short*          W1t   = (short*)(ws + OFFB_W1);
    short*          C2t   = (short*)(ws + OFFB_C2);
    float*          cst   = (float*)(ws + OFFB_CST);
    unsigned short* Bu    = (unsigned short*)(ws + OFFB_BU);
    unsigned short* ysbf  = (unsigned short*)(ws + OFFB_YS);
    float*          zend  = (float*)(ws + OFFB_ZEND);
    float*          carry = (float*)(ws + OFFB_CARRY);

    prep_consts<<<1, 256, 0, stream>>>(steps_raw, G_raw, A_raw, cst);
    prep_w<<<(HD * NN) / 512, 512, 0, stream>>>(B_mat, C_mat, W1t, C2t);

    // GEMM1 (fused cvt): Bu[32768 x 512](bf16) = bf16(x) * W1t^T ; 256 blocks
    gemm256_cvtA<HD, NN><<<(NN / 256) * (MROWS / 256), 512, 0, stream>>>(
        x, W1t, Bu);

    scan_phase1<<<BB * NCH, 512, 0, stream>>>(Bu, cst, zend);
    scan_phase2<<<BB, 512, 0, stream>>>(zend, cst, carry);
    scan_phase3<<<BB * NCH, 512, 0, stream>>>(Bu, cst, carry, ysbf);

    // GEMM2: out[32768 x 1024](f32) = ysbf * C2t^T + x*D ; 512 blocks (256^2)
    gemm256<NN, HD, true><<<(HD / 256) * (MROWS / 256), 512, 0, stream>>>(
        (const short*)ysbf, C2t, out, x, D_vec);
}